// Round 13
// baseline (211.315 us; speedup 1.0000x reference)
//
#include <hip/hip_runtime.h>
#include <hip/hip_fp16.h>
#include <math.h>

#define N_NODES 50000
#define N_EDGES 800000
#define N_GRAPHS 512
#define NBKT 196                          // ceil(50000/256) buckets
#define SENT N_NODES
#define CAP_T 6144                        // tmp slots/bucket
#define CAP_S 8192                        // sorted slots/bucket (padded max 7936)
#define GAT_NB 1563                       // ceil(6250 waves / 4)

typedef float v2f __attribute__((ext_vector_type(2)));

// workspace byte offsets (256B-aligned)
#define OFF_BCNT    0u                    // 196 ints (zeroed by memset)
#define OFF_DINV    1024u                 // 50000 floats
#define OFF_OFFS2   201216u               // 50000 int2
#define OFF_TMP     601344u               // 196*6144 uints
#define OFF_SORTED  5418240u              // 196*8192 ints
#define OFF_XS8_1   11840768u             // 50001*64 bytes fp8
#define OFF_XS8_2   15041024u             // 50001*64 bytes fp8
#define OFF_HBUF    18241280u             // 50000*64 fp32

// ---- binA: bin edges into fixed-capacity bucket runs (bucket = dst>>8) ----
__global__ __launch_bounds__(256) void binA(const int* __restrict__ src, const int* __restrict__ dst,
                                            int* __restrict__ bcnt, unsigned int* __restrict__ tmp,
                                            unsigned int* __restrict__ x1, unsigned int* __restrict__ x2) {
    __shared__ int cnt[NBKT], base[NBKT], cnt2[NBKT];
    int t = threadIdx.x;
    for (int j = t; j < NBKT; j += 256) { cnt[j] = 0; cnt2[j] = 0; }
    if (blockIdx.x == 0) {                 // zero fp8 sentinel row 50000 of both tables
        if (t < 16) x1[N_NODES * 16 + t] = 0;
        else if (t < 32) x2[N_NODES * 16 + (t - 16)] = 0;
    }
    __syncthreads();
    int e0 = blockIdx.x * 4096;
    int sA[16], dA[16];
#pragma unroll
    for (int i = 0; i < 16; ++i) {
        int e = e0 + i * 256 + t;
        if (e < N_EDGES) {
            sA[i] = src[e];
            dA[i] = dst[e];
            atomicAdd(&cnt[dA[i] >> 8], 1);
        } else dA[i] = -1;
    }
    __syncthreads();
    for (int j = t; j < NBKT; j += 256)
        base[j] = cnt[j] ? atomicAdd(&bcnt[j], cnt[j]) : 0;
    __syncthreads();
#pragma unroll
    for (int i = 0; i < 16; ++i) {
        if (dA[i] >= 0) {
            int b = dA[i] >> 8;
            int pos = base[b] + atomicAdd(&cnt2[b], 1);
            tmp[b * CAP_T + pos] = (unsigned int)sA[i] | ((unsigned int)(dA[i] & 255) << 17);  // src < 2^17
        }
    }
}

// ---- binB2: per bucket — LDS histogram + scan -> offs2/dinv; scatter; pad fill ----
__global__ __launch_bounds__(256) void binB2(const unsigned int* __restrict__ tmp,
                                             const int* __restrict__ bcnt,
                                             int* __restrict__ sorted, int2* __restrict__ offs2,
                                             float* __restrict__ dinv) {
    __shared__ int cnt[256];
    __shared__ int scn[256];
    __shared__ int cur[256];
    int b = blockIdx.x, t = threadIdx.x;
    cnt[t] = 0;
    __syncthreads();
    int m = bcnt[b];
    const unsigned int* tp = tmp + b * CAP_T;
    for (int e = t; e < m; e += 256) atomicAdd(&cnt[tp[e] >> 17], 1);
    __syncthreads();
    int deg = cnt[t];
    int pdeg = (deg + 7) & ~7;
    scn[t] = pdeg;
    __syncthreads();
    for (int d = 1; d < 256; d <<= 1) {
        int a = (t >= d) ? scn[t - d] : 0;
        __syncthreads();
        scn[t] += a;
        __syncthreads();
    }
    int beg = b * CAP_S + scn[t] - pdeg;
    int node = b * 256 + t;
    if (node < N_NODES) {
        offs2[node] = make_int2(beg, beg + pdeg);
        dinv[node] = rsqrtf(1.0f + (float)deg);
    }
    cur[t] = beg;
    __syncthreads();
    for (int e = t; e < m; e += 256) {
        unsigned int pk = tp[e];
        int p = atomicAdd(&cur[pk >> 17], 1);
        sorted[p] = (int)(pk & 0x1FFFFu);
    }
    __syncthreads();
    int ce = cur[t];                        // beg + deg
    for (int p = ce; p < beg + pdeg; ++p) sorted[p] = SENT;
}

// ---- GEMM layer 1: xs8 = fp8((X @ W1) * dinv[row]), K=128 ----
__global__ __launch_bounds__(256) void gemm1(const float* __restrict__ X, const float* __restrict__ W,
                                             const float* __restrict__ dinv, unsigned int* __restrict__ xs8) {
    __shared__ float sW[128 * 64];
    __shared__ float sX[16 * 132];
    int tid = threadIdx.x;
    {
        const float4* ws = (const float4*)W;
        float4* wd = (float4*)sW;
        for (int i = tid; i < 2048; i += 256) wd[i] = ws[i];
    }
    int row0 = blockIdx.x * 16;
    {
        const float4* xs = (const float4*)(X + row0 * 128);
        for (int i = tid; i < 512; i += 256) {
            int r = i >> 5, q = i & 31;
            *(float4*)&sX[r * 132 + 4 * q] = xs[r * 32 + q];
        }
    }
    __syncthreads();
    int r = tid >> 4;
    int cg = (tid & 15) * 4;
    int row = row0 + r;
    float a0 = 0, a1 = 0, a2 = 0, a3 = 0;
#pragma unroll 8
    for (int k = 0; k < 128; ++k) {
        float xv = sX[r * 132 + k];
        float4 w = *(const float4*)&sW[k * 64 + cg];
        a0 += xv * w.x; a1 += xv * w.y; a2 += xv * w.z; a3 += xv * w.w;
    }
    float s = dinv[row];
    unsigned int pk = 0;
    pk = __builtin_amdgcn_cvt_pk_fp8_f32(a0 * s, a1 * s, pk, false);
    pk = __builtin_amdgcn_cvt_pk_fp8_f32(a2 * s, a3 * s, pk, true);
    xs8[row * 16 + (cg >> 2)] = pk;
}

// ---- GEMM layer 2: xs8 = fp8((h1 @ W2) * dinv[row]), K=64 ----
__global__ __launch_bounds__(256) void gemm2(const float* __restrict__ X, const float* __restrict__ W,
                                             const float* __restrict__ dinv, unsigned int* __restrict__ xs8) {
    __shared__ float sW[64 * 64];
    __shared__ float sX[16][65];
    int tid = threadIdx.x;
    for (int i = tid; i < 64 * 64; i += 256) sW[i] = W[i];
    int row0 = blockIdx.x * 16;
    for (int i = tid; i < 16 * 64; i += 256) {
        int r = i >> 6, k = i & 63;
        sX[r][k] = X[(row0 + r) * 64 + k];
    }
    __syncthreads();
    int r = tid >> 4;
    int cg = (tid & 15) * 4;
    int row = row0 + r;
    float a0 = 0, a1 = 0, a2 = 0, a3 = 0;
#pragma unroll 8
    for (int k = 0; k < 64; ++k) {
        float xv = sX[r][k];
        float4 w = *(const float4*)&sW[k * 64 + cg];
        a0 += xv * w.x; a1 += xv * w.y; a2 += xv * w.z; a3 += xv * w.w;
    }
    float s = dinv[row];
    unsigned int pk = 0;
    pk = __builtin_amdgcn_cvt_pk_fp8_f32(a0 * s, a1 * s, pk, false);
    pk = __builtin_amdgcn_cvt_pk_fp8_f32(a2 * s, a3 * s, pk, true);
    xs8[row * 16 + (cg >> 2)] = pk;
}

// ---- streaming gather: wave owns 8 nodes; 8-deep row pipeline; shfl-held bounds ----
#define ADD_ROW(rv) { \
    v2f f0 = __builtin_amdgcn_cvt_pk_f32_fp8((rv).x, false); \
    v2f f1 = __builtin_amdgcn_cvt_pk_f32_fp8((rv).x, true); \
    v2f f2 = __builtin_amdgcn_cvt_pk_f32_fp8((rv).y, false); \
    v2f f3 = __builtin_amdgcn_cvt_pk_f32_fp8((rv).y, true); \
    a0 += f0.x; a1 += f0.y; a2 += f1.x; a3 += f1.y; \
    a4 += f2.x; a5 += f2.y; a6 += f3.x; a7 += f3.y; }

__global__ __launch_bounds__(256) void gather_m8(const unsigned char* __restrict__ xs8,
                                                 const int2* __restrict__ offs2,
                                                 const int* __restrict__ sorted,
                                                 const float* __restrict__ dinv,
                                                 const float* __restrict__ bias,
                                                 float* __restrict__ fout) {
    int wv = blockIdx.x * 4 + (threadIdx.x >> 6);
    int n0 = wv * 8;
    if (n0 >= N_NODES) return;                       // wave-uniform exit
    int lane = threadIdx.x & 63;
    int sub = lane >> 3, frag = lane & 7;
    int lk = lane & 7;
    int2 oe = offs2[n0 + lk];                        // lane k: node k's (beg,end)
    int e0 = __shfl(oe.x, 0);
    int E  = __shfl(oe.y, 7);
    int G  = (E - e0) >> 3;                          // total 8-edge groups for 8 nodes
    int bnd = (oe.x - e0) >> 3;                      // lane k: start group of node k
    float dvv = dinv[n0 + lk];                       // lane k: dinv of node k
    float4 bA = *(const float4*)(bias + frag * 8);
    float4 bB = *(const float4*)(bias + frag * 8 + 4);
    const int* sb = sorted + e0 + sub;
    int i0 = (0 < G) ? sb[0]  : SENT;
    int i1 = (1 < G) ? sb[8]  : SENT;
    int i2 = (2 < G) ? sb[16] : SENT;
    int i3 = (3 < G) ? sb[24] : SENT;
    int i4 = (4 < G) ? sb[32] : SENT;
    int i5 = (5 < G) ? sb[40] : SENT;
    int i6 = (6 < G) ? sb[48] : SENT;
    int i7 = (7 < G) ? sb[56] : SENT;
    int cur = 0;
    int nxt = __shfl(bnd, 1);                        // start of node 1 (0<7 always)
    uint2 sv = *(const uint2*)(xs8 + n0 * 64 + frag * 8);
    float dv = __shfl(dvv, 0);
    float a0 = 0, a1 = 0, a2 = 0, a3 = 0, a4 = 0, a5 = 0, a6 = 0, a7 = 0;

#define FLUSH_ADV() { \
    if (sub == 0) ADD_ROW(sv); \
    a0 += __shfl_xor(a0, 8);  a1 += __shfl_xor(a1, 8);  a2 += __shfl_xor(a2, 8);  a3 += __shfl_xor(a3, 8); \
    a4 += __shfl_xor(a4, 8);  a5 += __shfl_xor(a5, 8);  a6 += __shfl_xor(a6, 8);  a7 += __shfl_xor(a7, 8); \
    a0 += __shfl_xor(a0, 16); a1 += __shfl_xor(a1, 16); a2 += __shfl_xor(a2, 16); a3 += __shfl_xor(a3, 16); \
    a4 += __shfl_xor(a4, 16); a5 += __shfl_xor(a5, 16); a6 += __shfl_xor(a6, 16); a7 += __shfl_xor(a7, 16); \
    a0 += __shfl_xor(a0, 32); a1 += __shfl_xor(a1, 32); a2 += __shfl_xor(a2, 32); a3 += __shfl_xor(a3, 32); \
    a4 += __shfl_xor(a4, 32); a5 += __shfl_xor(a5, 32); a6 += __shfl_xor(a6, 32); a7 += __shfl_xor(a7, 32); \
    if (sub == 0) { \
        float4 w0, w1; \
        w0.x = fmaxf(a0 * dv + bA.x, 0.0f); w0.y = fmaxf(a1 * dv + bA.y, 0.0f); \
        w0.z = fmaxf(a2 * dv + bA.z, 0.0f); w0.w = fmaxf(a3 * dv + bA.w, 0.0f); \
        w1.x = fmaxf(a4 * dv + bB.x, 0.0f); w1.y = fmaxf(a5 * dv + bB.y, 0.0f); \
        w1.z = fmaxf(a6 * dv + bB.z, 0.0f); w1.w = fmaxf(a7 * dv + bB.w, 0.0f); \
        float* o = fout + (n0 + cur) * 64 + frag * 8; \
        *(float4*)(o) = w0; *(float4*)(o + 4) = w1; \
    } \
    a0 = a1 = a2 = a3 = a4 = a5 = a6 = a7 = 0.0f; \
    cur++; \
    if (cur < 8) { \
        sv = *(const uint2*)(xs8 + (n0 + cur) * 64 + frag * 8); \
        dv = __shfl(dvv, cur); \
        nxt = (cur < 7) ? __shfl(bnd, cur + 1) : G; \
    } }

#define STEP(j, rj) { \
    int gg = g + j; \
    while (cur < 7 && gg >= nxt) { FLUSH_ADV(); } \
    ADD_ROW(rj); }

    for (int g = 0; g < G; g += 8) {
        uint2 r0 = *(const uint2*)(xs8 + i0 * 64 + frag * 8);
        uint2 r1 = *(const uint2*)(xs8 + i1 * 64 + frag * 8);
        uint2 r2 = *(const uint2*)(xs8 + i2 * 64 + frag * 8);
        uint2 r3 = *(const uint2*)(xs8 + i3 * 64 + frag * 8);
        uint2 r4 = *(const uint2*)(xs8 + i4 * 64 + frag * 8);
        uint2 r5 = *(const uint2*)(xs8 + i5 * 64 + frag * 8);
        uint2 r6 = *(const uint2*)(xs8 + i6 * 64 + frag * 8);
        uint2 r7 = *(const uint2*)(xs8 + i7 * 64 + frag * 8);
        const int* np = sb + (g + 8) * 8;
        i0 = (g + 8  < G) ? np[0]  : SENT;
        i1 = (g + 9  < G) ? np[8]  : SENT;
        i2 = (g + 10 < G) ? np[16] : SENT;
        i3 = (g + 11 < G) ? np[24] : SENT;
        i4 = (g + 12 < G) ? np[32] : SENT;
        i5 = (g + 13 < G) ? np[40] : SENT;
        i6 = (g + 14 < G) ? np[48] : SENT;
        i7 = (g + 15 < G) ? np[56] : SENT;
        STEP(0, r0) STEP(1, r1) STEP(2, r2) STEP(3, r3)
        STEP(4, r4) STEP(5, r5) STEP(6, r6) STEP(7, r7)
    }
    while (cur < 8) { FLUSH_ADV(); }
#undef FLUSH_ADV
#undef STEP
}

// ---- fused pool (segmented mean over sorted batch) + fc head + log_softmax ----
__device__ __forceinline__ int lower_bound(const int* __restrict__ a, int n, int v) {
    int lo = 0, hi = n;
    while (lo < hi) { int m = (lo + hi) >> 1; if (a[m] < v) lo = m + 1; else hi = m; }
    return lo;
}

__global__ __launch_bounds__(256) void pool_head(const float* __restrict__ h2,
                                                 const int* __restrict__ batch,
                                                 const float* __restrict__ Wfc, const float* __restrict__ bfc,
                                                 const int* __restrict__ y, float* __restrict__ out) {
    __shared__ int s_beg, s_end;
    __shared__ float sh[4][64];
    __shared__ float pl[64];
    __shared__ float lg[4];
    int g = blockIdx.x;
    int t = threadIdx.x;
    if (t == 0) s_beg = lower_bound(batch, N_NODES, g);
    if (t == 1) s_end = lower_bound(batch, N_NODES, g + 1);
    __syncthreads();
    int beg = s_beg, end = s_end;
    int f = t & 63, seg = t >> 6;
    float s = 0.0f;
    for (int r = beg + seg; r < end; r += 4) s += h2[r * 64 + f];
    sh[seg][f] = s;
    __syncthreads();
    if (t < 64) {
        float p = sh[0][t] + sh[1][t] + sh[2][t] + sh[3][t];
        pl[t] = p / fmaxf((float)(end - beg), 1.0f);
    }
    __syncthreads();
    if (t < 4) {
        float l = bfc[t];
#pragma unroll
        for (int k = 0; k < 64; ++k) l += pl[k] * Wfc[k * 4 + t];
        lg[t] = l;
    }
    __syncthreads();
    if (t == 0) {
        float l0 = lg[0], l1 = lg[1], l2 = lg[2], l3 = lg[3];
        float m = fmaxf(fmaxf(l0, l1), fmaxf(l2, l3));
        float ss = expf(l0 - m) + expf(l1 - m) + expf(l2 - m) + expf(l3 - m);
        float lse = m + logf(ss);
        out[g * 4 + 0] = l0 - lse;
        out[g * 4 + 1] = l1 - lse;
        out[g * 4 + 2] = l2 - lse;
        out[g * 4 + 3] = l3 - lse;
        out[N_GRAPHS * 4 + g] = (float)y[g];
    }
}

extern "C" void kernel_launch(void* const* d_in, const int* in_sizes, int n_in,
                              void* d_out, int out_size, void* d_ws, size_t ws_size,
                              hipStream_t stream) {
    const float* x     = (const float*)d_in[0];
    const int*   ei    = (const int*)d_in[1];
    const int*   batch = (const int*)d_in[2];
    const int*   y     = (const int*)d_in[3];
    const float* W1    = (const float*)d_in[4];
    const float* b1    = (const float*)d_in[5];
    const float* W2    = (const float*)d_in[6];
    const float* b2    = (const float*)d_in[7];
    const float* Wfc   = (const float*)d_in[8];
    const float* bfc   = (const float*)d_in[9];
    float* out = (float*)d_out;

    const int* src = ei;
    const int* dst = ei + N_EDGES;

    char* wsb = (char*)d_ws;
    int*          bcnt   = (int*)(wsb + OFF_BCNT);
    float*        dinv   = (float*)(wsb + OFF_DINV);
    int2*         offs2  = (int2*)(wsb + OFF_OFFS2);
    unsigned int* tmp    = (unsigned int*)(wsb + OFF_TMP);
    int*          sorted = (int*)(wsb + OFF_SORTED);
    unsigned int* xs8_1  = (unsigned int*)(wsb + OFF_XS8_1);
    unsigned int* xs8_2  = (unsigned int*)(wsb + OFF_XS8_2);
    float*        hbuf   = (float*)(wsb + OFF_HBUF);

    hipMemsetAsync(bcnt, 0, 1024u, stream);

    binA<<<NBKT, 256, 0, stream>>>(src, dst, bcnt, tmp, xs8_1, xs8_2);
    binB2<<<NBKT, 256, 0, stream>>>(tmp, bcnt, sorted, offs2, dinv);

    // layer 1: 128 -> 64
    gemm1<<<N_NODES / 16, 256, 0, stream>>>(x, W1, dinv, xs8_1);
    gather_m8<<<GAT_NB, 256, 0, stream>>>((const unsigned char*)xs8_1, offs2, sorted, dinv, b1, hbuf);
    // layer 2: 64 -> 64
    gemm2<<<N_NODES / 16, 256, 0, stream>>>(hbuf, W2, dinv, xs8_2);
    gather_m8<<<GAT_NB, 256, 0, stream>>>((const unsigned char*)xs8_2, offs2, sorted, dinv, b2, hbuf);

    pool_head<<<N_GRAPHS, 256, 0, stream>>>(hbuf, batch, Wfc, bfc, y, out);
}

// Round 14
// 204.894 us; speedup vs baseline: 1.0313x; 1.0313x over previous
//
#include <hip/hip_runtime.h>
#include <hip/hip_fp16.h>
#include <math.h>

#define N_NODES 50000
#define N_EDGES 800000
#define N_GRAPHS 512
#define NBKT 196                          // ceil(50000/256) buckets
#define SENT N_NODES
#define CAP_T 6144                        // tmp slots/bucket
#define CAP_S 8192                        // sorted slots/bucket (padded max 7936)

typedef float v2f __attribute__((ext_vector_type(2)));

// workspace byte offsets (256B-aligned)
#define OFF_BCNT    0u                    // 196 ints (zeroed by memset)
#define OFF_DINV    1024u                 // 50000 floats
#define OFF_OFFS2   201216u               // 50000 int2
#define OFF_TMP     601344u               // 196*6144 uints
#define OFF_SORTED  5418240u              // 196*8192 ints
#define OFF_XS8_1   11840768u             // 50001*64 bytes fp8
#define OFF_XS8_2   15041024u             // 50001*64 bytes fp8
#define OFF_HBUF    18241280u             // 50000*64 fp32

// ---- binA v2: LDS-sort 4096 edges by bucket; dense copy-out to bucket runs ----
__global__ __launch_bounds__(256) void binA(const int* __restrict__ src, const int* __restrict__ dst,
                                            int* __restrict__ bcnt, unsigned int* __restrict__ tmp,
                                            unsigned int* __restrict__ x1, unsigned int* __restrict__ x2) {
    __shared__ int cnt[256];               // per-bucket count (196 used)
    __shared__ int lo[256];                // local exclusive offsets
    __shared__ int cnt2[256];
    __shared__ int baseg[256];             // global dst base per bucket
    __shared__ unsigned int ldsPK[4096];
    __shared__ int ldsDST[4096];
    int t = threadIdx.x;
    cnt[t] = 0; cnt2[t] = 0;
    if (blockIdx.x == 0) {                 // zero fp8 sentinel row 50000 of both tables
        if (t < 16) x1[N_NODES * 16 + t] = 0;
        else if (t < 32) x2[N_NODES * 16 + (t - 16)] = 0;
    }
    __syncthreads();
    int e0 = blockIdx.x * 4096;
    int nE = N_EDGES - e0; if (nE > 4096) nE = 4096;
    int sA[16], dA[16];
#pragma unroll
    for (int i = 0; i < 16; ++i) {
        int e = e0 + i * 256 + t;
        if (e < N_EDGES) {
            sA[i] = src[e];
            dA[i] = dst[e];
            atomicAdd(&cnt[dA[i] >> 8], 1);
        } else dA[i] = -1;
    }
    __syncthreads();
    {   // exclusive scan of cnt (Hillis-Steele over 256)
        int v = cnt[t];
        lo[t] = v;
        __syncthreads();
        for (int d = 1; d < 256; d <<= 1) {
            int a = (t >= d) ? lo[t - d] : 0;
            __syncthreads();
            lo[t] += a;
            __syncthreads();
        }
        int ex = lo[t] - v;
        __syncthreads();
        lo[t] = ex;                        // exclusive local offset
        baseg[t] = (t < NBKT && v) ? atomicAdd(&bcnt[t], v) : 0;
    }
    __syncthreads();
#pragma unroll
    for (int i = 0; i < 16; ++i) {
        if (dA[i] >= 0) {
            int b = dA[i] >> 8;
            int pl = lo[b] + atomicAdd(&cnt2[b], 1);
            ldsPK[pl] = (unsigned int)sA[i] | ((unsigned int)(dA[i] & 255) << 17);  // src < 2^17
            ldsDST[pl] = b * CAP_T + baseg[b] + (pl - lo[b]);
        }
    }
    __syncthreads();
    for (int p = t; p < nE; p += 256)      // consecutive p -> consecutive dst (dense runs)
        tmp[ldsDST[p]] = ldsPK[p];
}

// ---- binB2 v2: build padded sorted segment in LDS; dense int4 write-out ----
__global__ __launch_bounds__(256) void binB2(const unsigned int* __restrict__ tmp,
                                             const int* __restrict__ bcnt,
                                             int* __restrict__ sorted, int2* __restrict__ offs2,
                                             float* __restrict__ dinv) {
    __shared__ int cnt[256];
    __shared__ int scn[256];
    __shared__ int cur[256];
    __shared__ int ldsS[CAP_S];
    int b = blockIdx.x, t = threadIdx.x;
    cnt[t] = 0;
    __syncthreads();
    int m = bcnt[b];
    const unsigned int* tp = tmp + b * CAP_T;
    for (int e = t; e < m; e += 256) atomicAdd(&cnt[tp[e] >> 17], 1);
    __syncthreads();
    int deg = cnt[t];
    int pdeg = (deg + 7) & ~7;
    scn[t] = pdeg;
    __syncthreads();
    for (int d = 1; d < 256; d <<= 1) {
        int a = (t >= d) ? scn[t - d] : 0;
        __syncthreads();
        scn[t] += a;
        __syncthreads();
    }
    int begl = scn[t] - pdeg;              // bucket-local padded offset
    int ptot = scn[255];                   // total padded size (mult of 8)
    int node = b * 256 + t;
    if (node < N_NODES) {
        offs2[node] = make_int2(b * CAP_S + begl, b * CAP_S + begl + pdeg);
        dinv[node] = rsqrtf(1.0f + (float)deg);
    }
    cur[t] = begl;
    __syncthreads();
    for (int e = t; e < m; e += 256) {
        unsigned int pk = tp[e];
        int p = atomicAdd(&cur[pk >> 17], 1);
        ldsS[p] = (int)(pk & 0x1FFFFu);
    }
    __syncthreads();
    for (int p = cur[t]; p < begl + pdeg; ++p) ldsS[p] = SENT;   // pad fill in LDS
    __syncthreads();
    int4* dst4 = (int4*)(sorted + b * CAP_S);
    const int4* src4 = (const int4*)ldsS;
    for (int p = t; p < (ptot >> 2); p += 256) dst4[p] = src4[p];
}

// ---- GEMM layer 1: xs8 = fp8((X @ W1) * dinv[row]), K=128 ----
__global__ __launch_bounds__(256) void gemm1(const float* __restrict__ X, const float* __restrict__ W,
                                             const float* __restrict__ dinv, unsigned int* __restrict__ xs8) {
    __shared__ float sW[128 * 64];
    __shared__ float sX[16 * 132];
    int tid = threadIdx.x;
    {
        const float4* ws = (const float4*)W;
        float4* wd = (float4*)sW;
        for (int i = tid; i < 2048; i += 256) wd[i] = ws[i];
    }
    int row0 = blockIdx.x * 16;
    {
        const float4* xs = (const float4*)(X + row0 * 128);
        for (int i = tid; i < 512; i += 256) {
            int r = i >> 5, q = i & 31;
            *(float4*)&sX[r * 132 + 4 * q] = xs[r * 32 + q];
        }
    }
    __syncthreads();
    int r = tid >> 4;
    int cg = (tid & 15) * 4;
    int row = row0 + r;
    float a0 = 0, a1 = 0, a2 = 0, a3 = 0;
#pragma unroll 8
    for (int k = 0; k < 128; ++k) {
        float xv = sX[r * 132 + k];
        float4 w = *(const float4*)&sW[k * 64 + cg];
        a0 += xv * w.x; a1 += xv * w.y; a2 += xv * w.z; a3 += xv * w.w;
    }
    float s = dinv[row];
    unsigned int pk = 0;
    pk = __builtin_amdgcn_cvt_pk_fp8_f32(a0 * s, a1 * s, pk, false);
    pk = __builtin_amdgcn_cvt_pk_fp8_f32(a2 * s, a3 * s, pk, true);
    xs8[row * 16 + (cg >> 2)] = pk;
}

// ---- GEMM layer 2: xs8 = fp8((h1 @ W2) * dinv[row]), K=64 ----
__global__ __launch_bounds__(256) void gemm2(const float* __restrict__ X, const float* __restrict__ W,
                                             const float* __restrict__ dinv, unsigned int* __restrict__ xs8) {
    __shared__ float sW[64 * 64];
    __shared__ float sX[16][65];
    int tid = threadIdx.x;
    for (int i = tid; i < 64 * 64; i += 256) sW[i] = W[i];
    int row0 = blockIdx.x * 16;
    for (int i = tid; i < 16 * 64; i += 256) {
        int r = i >> 6, k = i & 63;
        sX[r][k] = X[(row0 + r) * 64 + k];
    }
    __syncthreads();
    int r = tid >> 4;
    int cg = (tid & 15) * 4;
    int row = row0 + r;
    float a0 = 0, a1 = 0, a2 = 0, a3 = 0;
#pragma unroll 8
    for (int k = 0; k < 64; ++k) {
        float xv = sX[r][k];
        float4 w = *(const float4*)&sW[k * 64 + cg];
        a0 += xv * w.x; a1 += xv * w.y; a2 += xv * w.z; a3 += xv * w.w;
    }
    float s = dinv[row];
    unsigned int pk = 0;
    pk = __builtin_amdgcn_cvt_pk_fp8_f32(a0 * s, a1 * s, pk, false);
    pk = __builtin_amdgcn_cvt_pk_fp8_f32(a2 * s, a3 * s, pk, true);
    xs8[row * 16 + (cg >> 2)] = pk;
}

// ---- multi-node streaming gather (fp8 rows, 64B each; 4 nodes/wave) ----
#define ADD_ROW(rv) { \
    v2f f0 = __builtin_amdgcn_cvt_pk_f32_fp8((rv).x, false); \
    v2f f1 = __builtin_amdgcn_cvt_pk_f32_fp8((rv).x, true); \
    v2f f2 = __builtin_amdgcn_cvt_pk_f32_fp8((rv).y, false); \
    v2f f3 = __builtin_amdgcn_cvt_pk_f32_fp8((rv).y, true); \
    a0 += f0.x; a1 += f0.y; a2 += f1.x; a3 += f1.y; \
    a4 += f2.x; a5 += f2.y; a6 += f3.x; a7 += f3.y; }

__global__ __launch_bounds__(256) void gather_m(const unsigned char* __restrict__ xs8,
                                                const int2* __restrict__ offs2,
                                                const int* __restrict__ sorted,
                                                const float* __restrict__ dinv,
                                                const float* __restrict__ bias,
                                                float* __restrict__ fout) {
    int wv = blockIdx.x * 4 + (threadIdx.x >> 6);  // 12500 waves, 4 nodes each (same bucket)
    int lane = threadIdx.x & 63;
    int sub = lane >> 3, frag = lane & 7;
    int n0 = wv * 4;
    int2 oe = offs2[n0 + (lane < 4 ? lane : 3)];
    int e0 = __shfl(oe.x, 0), e1 = __shfl(oe.x, 1), e2 = __shfl(oe.x, 2);
    int e3 = __shfl(oe.x, 3), e4 = __shfl(oe.y, 3);
    int G   = (e4 - e0) >> 3;
    int nb1 = (e1 - e0) >> 3, nb2 = (e2 - e0) >> 3, nb3 = (e3 - e0) >> 3;
    const int* sb = sorted + e0 + sub;
    int i0 = (0 < G) ? sb[0]  : SENT;
    int i1 = (1 < G) ? sb[8]  : SENT;
    int i2 = (2 < G) ? sb[16] : SENT;
    int i3 = (3 < G) ? sb[24] : SENT;
    float4 bA = *(const float4*)(bias + frag * 8);
    float4 bB = *(const float4*)(bias + frag * 8 + 4);
    int cur = 0;
    uint2 sv = *(const uint2*)(xs8 + n0 * 64 + frag * 8);
    float dv = dinv[n0];
    float a0 = 0, a1 = 0, a2 = 0, a3 = 0, a4 = 0, a5 = 0, a6 = 0, a7 = 0;

#define FLUSH_ADV() { \
    if (sub == 0) ADD_ROW(sv); \
    a0 += __shfl_xor(a0, 8);  a1 += __shfl_xor(a1, 8);  a2 += __shfl_xor(a2, 8);  a3 += __shfl_xor(a3, 8); \
    a4 += __shfl_xor(a4, 8);  a5 += __shfl_xor(a5, 8);  a6 += __shfl_xor(a6, 8);  a7 += __shfl_xor(a7, 8); \
    a0 += __shfl_xor(a0, 16); a1 += __shfl_xor(a1, 16); a2 += __shfl_xor(a2, 16); a3 += __shfl_xor(a3, 16); \
    a4 += __shfl_xor(a4, 16); a5 += __shfl_xor(a5, 16); a6 += __shfl_xor(a6, 16); a7 += __shfl_xor(a7, 16); \
    a0 += __shfl_xor(a0, 32); a1 += __shfl_xor(a1, 32); a2 += __shfl_xor(a2, 32); a3 += __shfl_xor(a3, 32); \
    a4 += __shfl_xor(a4, 32); a5 += __shfl_xor(a5, 32); a6 += __shfl_xor(a6, 32); a7 += __shfl_xor(a7, 32); \
    if (sub == 0) { \
        float4 w0, w1; \
        w0.x = fmaxf(a0 * dv + bA.x, 0.0f); w0.y = fmaxf(a1 * dv + bA.y, 0.0f); \
        w0.z = fmaxf(a2 * dv + bA.z, 0.0f); w0.w = fmaxf(a3 * dv + bA.w, 0.0f); \
        w1.x = fmaxf(a4 * dv + bB.x, 0.0f); w1.y = fmaxf(a5 * dv + bB.y, 0.0f); \
        w1.z = fmaxf(a6 * dv + bB.z, 0.0f); w1.w = fmaxf(a7 * dv + bB.w, 0.0f); \
        float* o = fout + (n0 + cur) * 64 + frag * 8; \
        *(float4*)(o) = w0; *(float4*)(o + 4) = w1; \
    } \
    a0 = a1 = a2 = a3 = a4 = a5 = a6 = a7 = 0.0f; \
    cur++; \
    if (cur < 4) { \
        sv = *(const uint2*)(xs8 + (n0 + cur) * 64 + frag * 8); \
        dv = dinv[n0 + cur]; \
    } }

#define BND_NXT() (cur == 0 ? nb1 : cur == 1 ? nb2 : cur == 2 ? nb3 : G)

    for (int g = 0; g < G; g += 4) {
        uint2 r0 = *(const uint2*)(xs8 + i0 * 64 + frag * 8);
        uint2 r1 = *(const uint2*)(xs8 + i1 * 64 + frag * 8);
        uint2 r2 = *(const uint2*)(xs8 + i2 * 64 + frag * 8);
        uint2 r3 = *(const uint2*)(xs8 + i3 * 64 + frag * 8);
        const int* np = sb + (g + 4) * 8;
        i0 = (g + 4 < G) ? np[0]  : SENT;
        i1 = (g + 5 < G) ? np[8]  : SENT;
        i2 = (g + 6 < G) ? np[16] : SENT;
        i3 = (g + 7 < G) ? np[24] : SENT;
        {   int gg = g;
            int nxt = BND_NXT();
            while (cur < 4 && gg >= nxt) { FLUSH_ADV(); nxt = BND_NXT(); }
            ADD_ROW(r0); }
        if (g + 1 < G) {
            int gg = g + 1;
            int nxt = BND_NXT();
            while (cur < 4 && gg >= nxt) { FLUSH_ADV(); nxt = BND_NXT(); }
            ADD_ROW(r1);
        }
        if (g + 2 < G) {
            int gg = g + 2;
            int nxt = BND_NXT();
            while (cur < 4 && gg >= nxt) { FLUSH_ADV(); nxt = BND_NXT(); }
            ADD_ROW(r2);
        }
        if (g + 3 < G) {
            int gg = g + 3;
            int nxt = BND_NXT();
            while (cur < 4 && gg >= nxt) { FLUSH_ADV(); nxt = BND_NXT(); }
            ADD_ROW(r3);
        }
    }
    while (cur < 4) { FLUSH_ADV(); }
#undef FLUSH_ADV
#undef BND_NXT
}

// ---- fused pool (segmented mean over sorted batch) + fc head + log_softmax ----
__device__ __forceinline__ int lower_bound(const int* __restrict__ a, int n, int v) {
    int lo = 0, hi = n;
    while (lo < hi) { int m = (lo + hi) >> 1; if (a[m] < v) lo = m + 1; else hi = m; }
    return lo;
}

__global__ __launch_bounds__(256) void pool_head(const float* __restrict__ h2,
                                                 const int* __restrict__ batch,
                                                 const float* __restrict__ Wfc, const float* __restrict__ bfc,
                                                 const int* __restrict__ y, float* __restrict__ out) {
    __shared__ int s_beg, s_end;
    __shared__ float sh[4][64];
    __shared__ float pl[64];
    __shared__ float lg[4];
    int g = blockIdx.x;
    int t = threadIdx.x;
    if (t == 0) s_beg = lower_bound(batch, N_NODES, g);
    if (t == 1) s_end = lower_bound(batch, N_NODES, g + 1);
    __syncthreads();
    int beg = s_beg, end = s_end;
    int f = t & 63, seg = t >> 6;
    float s = 0.0f;
    for (int r = beg + seg; r < end; r += 4) s += h2[r * 64 + f];
    sh[seg][f] = s;
    __syncthreads();
    if (t < 64) {
        float p = sh[0][t] + sh[1][t] + sh[2][t] + sh[3][t];
        pl[t] = p / fmaxf((float)(end - beg), 1.0f);
    }
    __syncthreads();
    if (t < 4) {
        float l = bfc[t];
#pragma unroll
        for (int k = 0; k < 64; ++k) l += pl[k] * Wfc[k * 4 + t];
        lg[t] = l;
    }
    __syncthreads();
    if (t == 0) {
        float l0 = lg[0], l1 = lg[1], l2 = lg[2], l3 = lg[3];
        float m = fmaxf(fmaxf(l0, l1), fmaxf(l2, l3));
        float ss = expf(l0 - m) + expf(l1 - m) + expf(l2 - m) + expf(l3 - m);
        float lse = m + logf(ss);
        out[g * 4 + 0] = l0 - lse;
        out[g * 4 + 1] = l1 - lse;
        out[g * 4 + 2] = l2 - lse;
        out[g * 4 + 3] = l3 - lse;
        out[N_GRAPHS * 4 + g] = (float)y[g];
    }
}

extern "C" void kernel_launch(void* const* d_in, const int* in_sizes, int n_in,
                              void* d_out, int out_size, void* d_ws, size_t ws_size,
                              hipStream_t stream) {
    const float* x     = (const float*)d_in[0];
    const int*   ei    = (const int*)d_in[1];
    const int*   batch = (const int*)d_in[2];
    const int*   y     = (const int*)d_in[3];
    const float* W1    = (const float*)d_in[4];
    const float* b1    = (const float*)d_in[5];
    const float* W2    = (const float*)d_in[6];
    const float* b2    = (const float*)d_in[7];
    const float* Wfc   = (const float*)d_in[8];
    const float* bfc   = (const float*)d_in[9];
    float* out = (float*)d_out;

    const int* src = ei;
    const int* dst = ei + N_EDGES;

    char* wsb = (char*)d_ws;
    int*          bcnt   = (int*)(wsb + OFF_BCNT);
    float*        dinv   = (float*)(wsb + OFF_DINV);
    int2*         offs2  = (int2*)(wsb + OFF_OFFS2);
    unsigned int* tmp    = (unsigned int*)(wsb + OFF_TMP);
    int*          sorted = (int*)(wsb + OFF_SORTED);
    unsigned int* xs8_1  = (unsigned int*)(wsb + OFF_XS8_1);
    unsigned int* xs8_2  = (unsigned int*)(wsb + OFF_XS8_2);
    float*        hbuf   = (float*)(wsb + OFF_HBUF);

    hipMemsetAsync(bcnt, 0, 1024u, stream);

    binA<<<NBKT, 256, 0, stream>>>(src, dst, bcnt, tmp, xs8_1, xs8_2);
    binB2<<<NBKT, 256, 0, stream>>>(tmp, bcnt, sorted, offs2, dinv);

    // layer 1: 128 -> 64
    gemm1<<<N_NODES / 16, 256, 0, stream>>>(x, W1, dinv, xs8_1);
    gather_m<<<N_NODES / 16, 256, 0, stream>>>((const unsigned char*)xs8_1, offs2, sorted, dinv, b1, hbuf);
    // layer 2: 64 -> 64
    gemm2<<<N_NODES / 16, 256, 0, stream>>>(hbuf, W2, dinv, xs8_2);
    gather_m<<<N_NODES / 16, 256, 0, stream>>>((const unsigned char*)xs8_2, offs2, sorted, dinv, b2, hbuf);

    pool_head<<<N_GRAPHS, 256, 0, stream>>>(hbuf, batch, Wfc, bfc, y, out);
}

// Round 15
// 196.559 us; speedup vs baseline: 1.0751x; 1.0424x over previous
//
#include <hip/hip_runtime.h>
#include <hip/hip_fp16.h>
#include <math.h>

#define N_NODES 50000
#define N_EDGES 800000
#define N_GRAPHS 512
#define NBKT 196                          // ceil(50000/256) buckets
#define SENT N_NODES
#define CAP_T 6144                        // tmp slots/bucket
#define CAP_S 8192                        // sorted slots/bucket (padded max 7936)

typedef float v2f __attribute__((ext_vector_type(2)));

// workspace byte offsets (256B-aligned)
#define OFF_BCNT    0u                    // 196 ints (zeroed by memset)
#define OFF_DINV    1024u                 // 50000 floats
#define OFF_OFFS2   201216u               // 50000 int2
#define OFF_TMP     601344u               // 196*6144 uints
#define OFF_SORTED  5418240u              // 196*8192 ints
#define OFF_XS8_1   11840768u             // 50001*64 bytes fp8
#define OFF_XS8_2   15041024u             // 50001*64 bytes fp8
#define OFF_H2      18241280u             // 50000*64 fp16

// ---- binA: LDS-sort 4096 edges by bucket; dense copy-out to bucket runs ----
__global__ __launch_bounds__(256) void binA(const int* __restrict__ src, const int* __restrict__ dst,
                                            int* __restrict__ bcnt, unsigned int* __restrict__ tmp,
                                            unsigned int* __restrict__ x1, unsigned int* __restrict__ x2) {
    __shared__ int cnt[256];
    __shared__ int lo[256];
    __shared__ int cnt2[256];
    __shared__ int baseg[256];
    __shared__ unsigned int ldsPK[4096];
    __shared__ int ldsDST[4096];
    int t = threadIdx.x;
    cnt[t] = 0; cnt2[t] = 0;
    if (blockIdx.x == 0) {                 // zero fp8 sentinel row 50000 of both tables
        if (t < 16) x1[N_NODES * 16 + t] = 0;
        else if (t < 32) x2[N_NODES * 16 + (t - 16)] = 0;
    }
    __syncthreads();
    int e0 = blockIdx.x * 4096;
    int nE = N_EDGES - e0; if (nE > 4096) nE = 4096;
    int sA[16], dA[16];
#pragma unroll
    for (int i = 0; i < 16; ++i) {
        int e = e0 + i * 256 + t;
        if (e < N_EDGES) {
            sA[i] = src[e];
            dA[i] = dst[e];
            atomicAdd(&cnt[dA[i] >> 8], 1);
        } else dA[i] = -1;
    }
    __syncthreads();
    {
        int v = cnt[t];
        lo[t] = v;
        __syncthreads();
        for (int d = 1; d < 256; d <<= 1) {
            int a = (t >= d) ? lo[t - d] : 0;
            __syncthreads();
            lo[t] += a;
            __syncthreads();
        }
        int ex = lo[t] - v;
        __syncthreads();
        lo[t] = ex;
        baseg[t] = (t < NBKT && v) ? atomicAdd(&bcnt[t], v) : 0;
    }
    __syncthreads();
#pragma unroll
    for (int i = 0; i < 16; ++i) {
        if (dA[i] >= 0) {
            int b = dA[i] >> 8;
            int pl = lo[b] + atomicAdd(&cnt2[b], 1);
            ldsPK[pl] = (unsigned int)sA[i] | ((unsigned int)(dA[i] & 255) << 17);  // src < 2^17
            ldsDST[pl] = b * CAP_T + baseg[b] + (pl - lo[b]);
        }
    }
    __syncthreads();
    for (int p = t; p < nE; p += 256)
        tmp[ldsDST[p]] = ldsPK[p];
}

// ---- binB2: build padded sorted segment in LDS; dense int4 write-out ----
__global__ __launch_bounds__(256) void binB2(const unsigned int* __restrict__ tmp,
                                             const int* __restrict__ bcnt,
                                             int* __restrict__ sorted, int2* __restrict__ offs2,
                                             float* __restrict__ dinv) {
    __shared__ int cnt[256];
    __shared__ int scn[256];
    __shared__ int cur[256];
    __shared__ int ldsS[CAP_S];
    int b = blockIdx.x, t = threadIdx.x;
    cnt[t] = 0;
    __syncthreads();
    int m = bcnt[b];
    const unsigned int* tp = tmp + b * CAP_T;
    for (int e = t; e < m; e += 256) atomicAdd(&cnt[tp[e] >> 17], 1);
    __syncthreads();
    int deg = cnt[t];
    int pdeg = (deg + 7) & ~7;
    scn[t] = pdeg;
    __syncthreads();
    for (int d = 1; d < 256; d <<= 1) {
        int a = (t >= d) ? scn[t - d] : 0;
        __syncthreads();
        scn[t] += a;
        __syncthreads();
    }
    int begl = scn[t] - pdeg;
    int ptot = scn[255];
    int node = b * 256 + t;
    if (node < N_NODES) {
        offs2[node] = make_int2(b * CAP_S + begl, b * CAP_S + begl + pdeg);
        dinv[node] = rsqrtf(1.0f + (float)deg);
    }
    cur[t] = begl;
    __syncthreads();
    for (int e = t; e < m; e += 256) {
        unsigned int pk = tp[e];
        int p = atomicAdd(&cur[pk >> 17], 1);
        ldsS[p] = (int)(pk & 0x1FFFFu);
    }
    __syncthreads();
    for (int p = cur[t]; p < begl + pdeg; ++p) ldsS[p] = SENT;
    __syncthreads();
    int4* dst4 = (int4*)(sorted + b * CAP_S);
    const int4* src4 = (const int4*)ldsS;
    for (int p = t; p < (ptot >> 2); p += 256) dst4[p] = src4[p];
}

// ---- GEMM layer 1: xs8 = fp8((X @ W1) * dinv[row]), K=128 ----
__global__ __launch_bounds__(256) void gemm1(const float* __restrict__ X, const float* __restrict__ W,
                                             const float* __restrict__ dinv, unsigned int* __restrict__ xs8) {
    __shared__ float sW[128 * 64];
    __shared__ float sX[16 * 132];
    int tid = threadIdx.x;
    {
        const float4* ws = (const float4*)W;
        float4* wd = (float4*)sW;
        for (int i = tid; i < 2048; i += 256) wd[i] = ws[i];
    }
    int row0 = blockIdx.x * 16;
    {
        const float4* xs = (const float4*)(X + row0 * 128);
        for (int i = tid; i < 512; i += 256) {
            int r = i >> 5, q = i & 31;
            *(float4*)&sX[r * 132 + 4 * q] = xs[r * 32 + q];
        }
    }
    __syncthreads();
    int r = tid >> 4;
    int cg = (tid & 15) * 4;
    int row = row0 + r;
    float a0 = 0, a1 = 0, a2 = 0, a3 = 0;
#pragma unroll 8
    for (int k = 0; k < 128; ++k) {
        float xv = sX[r * 132 + k];
        float4 w = *(const float4*)&sW[k * 64 + cg];
        a0 += xv * w.x; a1 += xv * w.y; a2 += xv * w.z; a3 += xv * w.w;
    }
    float s = dinv[row];
    unsigned int pk = 0;
    pk = __builtin_amdgcn_cvt_pk_fp8_f32(a0 * s, a1 * s, pk, false);
    pk = __builtin_amdgcn_cvt_pk_fp8_f32(a2 * s, a3 * s, pk, true);
    xs8[row * 16 + (cg >> 2)] = pk;
}

// ---- shared gather machinery ----
#define ADD_ROW(rv) { \
    v2f f0 = __builtin_amdgcn_cvt_pk_f32_fp8((rv).x, false); \
    v2f f1 = __builtin_amdgcn_cvt_pk_f32_fp8((rv).x, true); \
    v2f f2 = __builtin_amdgcn_cvt_pk_f32_fp8((rv).y, false); \
    v2f f3 = __builtin_amdgcn_cvt_pk_f32_fp8((rv).y, true); \
    a0 += f0.x; a1 += f0.y; a2 += f1.x; a3 += f1.y; \
    a4 += f2.x; a5 += f2.y; a6 += f3.x; a7 += f3.y; }

#define RED_SUB() { \
    a0 += __shfl_xor(a0, 8);  a1 += __shfl_xor(a1, 8);  a2 += __shfl_xor(a2, 8);  a3 += __shfl_xor(a3, 8); \
    a4 += __shfl_xor(a4, 8);  a5 += __shfl_xor(a5, 8);  a6 += __shfl_xor(a6, 8);  a7 += __shfl_xor(a7, 8); \
    a0 += __shfl_xor(a0, 16); a1 += __shfl_xor(a1, 16); a2 += __shfl_xor(a2, 16); a3 += __shfl_xor(a3, 16); \
    a4 += __shfl_xor(a4, 16); a5 += __shfl_xor(a5, 16); a6 += __shfl_xor(a6, 16); a7 += __shfl_xor(a7, 16); \
    a0 += __shfl_xor(a0, 32); a1 += __shfl_xor(a1, 32); a2 += __shfl_xor(a2, 32); a3 += __shfl_xor(a3, 32); \
    a4 += __shfl_xor(a4, 32); a5 += __shfl_xor(a5, 32); a6 += __shfl_xor(a6, 32); a7 += __shfl_xor(a7, 32); }

#define GATHER_BODY(FLUSH_ADV) \
    int lane = threadIdx.x & 63; \
    int sub = lane >> 3, frag = lane & 7; \
    int n0 = wv * 4; \
    int2 oe = offs2[n0 + (lane < 4 ? lane : 3)]; \
    int e0 = __shfl(oe.x, 0), e1 = __shfl(oe.x, 1), e2 = __shfl(oe.x, 2); \
    int e3 = __shfl(oe.x, 3), e4 = __shfl(oe.y, 3); \
    int G   = (e4 - e0) >> 3; \
    int nb1 = (e1 - e0) >> 3, nb2 = (e2 - e0) >> 3, nb3 = (e3 - e0) >> 3; \
    const int* sb = sorted + e0 + sub; \
    int i0 = (0 < G) ? sb[0]  : SENT; \
    int i1 = (1 < G) ? sb[8]  : SENT; \
    int i2 = (2 < G) ? sb[16] : SENT; \
    int i3 = (3 < G) ? sb[24] : SENT; \
    float4 bA = *(const float4*)(bias + frag * 8); \
    float4 bB = *(const float4*)(bias + frag * 8 + 4); \
    int cur = 0; \
    uint2 sv = *(const uint2*)(xs8 + n0 * 64 + frag * 8); \
    float dv = dinv[n0]; \
    float a0 = 0, a1 = 0, a2 = 0, a3 = 0, a4 = 0, a5 = 0, a6 = 0, a7 = 0; \
    for (int g = 0; g < G; g += 4) { \
        uint2 r0 = *(const uint2*)(xs8 + i0 * 64 + frag * 8); \
        uint2 r1 = *(const uint2*)(xs8 + i1 * 64 + frag * 8); \
        uint2 r2 = *(const uint2*)(xs8 + i2 * 64 + frag * 8); \
        uint2 r3 = *(const uint2*)(xs8 + i3 * 64 + frag * 8); \
        const int* np = sb + (g + 4) * 8; \
        i0 = (g + 4 < G) ? np[0]  : SENT; \
        i1 = (g + 5 < G) ? np[8]  : SENT; \
        i2 = (g + 6 < G) ? np[16] : SENT; \
        i3 = (g + 7 < G) ? np[24] : SENT; \
        {   int gg = g; \
            int nxt = BND_NXT(); \
            while (cur < 4 && gg >= nxt) { FLUSH_ADV(); nxt = BND_NXT(); } \
            ADD_ROW(r0); } \
        if (g + 1 < G) { \
            int gg = g + 1; \
            int nxt = BND_NXT(); \
            while (cur < 4 && gg >= nxt) { FLUSH_ADV(); nxt = BND_NXT(); } \
            ADD_ROW(r1); \
        } \
        if (g + 2 < G) { \
            int gg = g + 2; \
            int nxt = BND_NXT(); \
            while (cur < 4 && gg >= nxt) { FLUSH_ADV(); nxt = BND_NXT(); } \
            ADD_ROW(r2); \
        } \
        if (g + 3 < G) { \
            int gg = g + 3; \
            int nxt = BND_NXT(); \
            while (cur < 4 && gg >= nxt) { FLUSH_ADV(); nxt = BND_NXT(); } \
            ADD_ROW(r3); \
        } \
    } \
    while (cur < 4) { FLUSH_ADV(); }

#define BND_NXT() (cur == 0 ? nb1 : cur == 1 ? nb2 : cur == 2 ? nb3 : G)

// ---- gather layer 1 + fused W2 GEMM: h rows -> LDS; block epilogue emits xs8_2 ----
__global__ __launch_bounds__(256) void gather_fuse(const unsigned char* __restrict__ xs8,
                                                   const int2* __restrict__ offs2,
                                                   const int* __restrict__ sorted,
                                                   const float* __restrict__ dinv,
                                                   const float* __restrict__ bias,
                                                   const float* __restrict__ W2,
                                                   unsigned int* __restrict__ xs8o) {
    __shared__ float sW2[64 * 64];
    __shared__ float sH[16][64];
    {
        const float4* ws = (const float4*)W2;
        float4* wd = (float4*)sW2;
        for (int i = threadIdx.x; i < 1024; i += 256) wd[i] = ws[i];
    }
    int wvl = threadIdx.x >> 6;                    // wave 0..3 in block
    int wv = blockIdx.x * 4 + wvl;                 // 12500 waves, 4 nodes each

#define FLUSH_LDS() { \
    if (sub == 0) ADD_ROW(sv); \
    RED_SUB(); \
    if (sub == 0) { \
        float4 w0, w1; \
        w0.x = fmaxf(a0 * dv + bA.x, 0.0f); w0.y = fmaxf(a1 * dv + bA.y, 0.0f); \
        w0.z = fmaxf(a2 * dv + bA.z, 0.0f); w0.w = fmaxf(a3 * dv + bA.w, 0.0f); \
        w1.x = fmaxf(a4 * dv + bB.x, 0.0f); w1.y = fmaxf(a5 * dv + bB.y, 0.0f); \
        w1.z = fmaxf(a6 * dv + bB.z, 0.0f); w1.w = fmaxf(a7 * dv + bB.w, 0.0f); \
        *(float4*)&sH[wvl * 4 + cur][frag * 8]     = w0; \
        *(float4*)&sH[wvl * 4 + cur][frag * 8 + 4] = w1; \
    } \
    a0 = a1 = a2 = a3 = a4 = a5 = a6 = a7 = 0.0f; \
    cur++; \
    if (cur < 4) { \
        sv = *(const uint2*)(xs8 + (n0 + cur) * 64 + frag * 8); \
        dv = dinv[n0 + cur]; \
    } }

    GATHER_BODY(FLUSH_LDS)
#undef FLUSH_LDS
    __syncthreads();
    // block epilogue: xs2[16 nodes x 64] = (sH @ W2) * dinv
    int r = threadIdx.x >> 4;                      // 0..15 local node
    int cg = (threadIdx.x & 15) * 4;               // col group
    int node = blockIdx.x * 16 + r;
    float b0 = 0, b1 = 0, b2 = 0, b3 = 0;
#pragma unroll 8
    for (int k = 0; k < 64; ++k) {
        float hv = sH[r][k];
        float4 w = *(const float4*)&sW2[k * 64 + cg];
        b0 += hv * w.x; b1 += hv * w.y; b2 += hv * w.z; b3 += hv * w.w;
    }
    float s = dinv[node];
    unsigned int pk = 0;
    pk = __builtin_amdgcn_cvt_pk_fp8_f32(b0 * s, b1 * s, pk, false);
    pk = __builtin_amdgcn_cvt_pk_fp8_f32(b2 * s, b3 * s, pk, true);
    xs8o[node * 16 + (cg >> 2)] = pk;
}

// ---- gather layer 2: writes h2 as fp16 ----
__global__ __launch_bounds__(256) void gather_h2(const unsigned char* __restrict__ xs8,
                                                 const int2* __restrict__ offs2,
                                                 const int* __restrict__ sorted,
                                                 const float* __restrict__ dinv,
                                                 const float* __restrict__ bias,
                                                 __half* __restrict__ h2) {
    int wv = blockIdx.x * 4 + (threadIdx.x >> 6);

#define FLUSH_H2() { \
    if (sub == 0) ADD_ROW(sv); \
    RED_SUB(); \
    if (sub == 0) { \
        float v0 = fmaxf(a0 * dv + bA.x, 0.0f), v1 = fmaxf(a1 * dv + bA.y, 0.0f); \
        float v2 = fmaxf(a2 * dv + bA.z, 0.0f), v3 = fmaxf(a3 * dv + bA.w, 0.0f); \
        float v4 = fmaxf(a4 * dv + bB.x, 0.0f), v5 = fmaxf(a5 * dv + bB.y, 0.0f); \
        float v6 = fmaxf(a6 * dv + bB.z, 0.0f), v7 = fmaxf(a7 * dv + bB.w, 0.0f); \
        __half2 p0 = __floats2half2_rn(v0, v1), p1 = __floats2half2_rn(v2, v3); \
        __half2 p2 = __floats2half2_rn(v4, v5), p3 = __floats2half2_rn(v6, v7); \
        uint4 pk; \
        pk.x = *(unsigned int*)&p0; pk.y = *(unsigned int*)&p1; \
        pk.z = *(unsigned int*)&p2; pk.w = *(unsigned int*)&p3; \
        *(uint4*)(h2 + (n0 + cur) * 64 + frag * 8) = pk; \
    } \
    a0 = a1 = a2 = a3 = a4 = a5 = a6 = a7 = 0.0f; \
    cur++; \
    if (cur < 4) { \
        sv = *(const uint2*)(xs8 + (n0 + cur) * 64 + frag * 8); \
        dv = dinv[n0 + cur]; \
    } }

    GATHER_BODY(FLUSH_H2)
#undef FLUSH_H2
}

// ---- fused pool (segmented mean over sorted batch) + fc head + log_softmax ----
__device__ __forceinline__ int lower_bound(const int* __restrict__ a, int n, int v) {
    int lo = 0, hi = n;
    while (lo < hi) { int m = (lo + hi) >> 1; if (a[m] < v) lo = m + 1; else hi = m; }
    return lo;
}

__global__ __launch_bounds__(256) void pool_head(const __half* __restrict__ h2,
                                                 const int* __restrict__ batch,
                                                 const float* __restrict__ Wfc, const float* __restrict__ bfc,
                                                 const int* __restrict__ y, float* __restrict__ out) {
    __shared__ int s_beg, s_end;
    __shared__ float sh[4][64];
    __shared__ float pl[64];
    __shared__ float lg[4];
    int g = blockIdx.x;
    int t = threadIdx.x;
    if (t == 0) s_beg = lower_bound(batch, N_NODES, g);
    if (t == 1) s_end = lower_bound(batch, N_NODES, g + 1);
    __syncthreads();
    int beg = s_beg, end = s_end;
    int f = t & 63, seg = t >> 6;
    float s = 0.0f;
    for (int r = beg + seg; r < end; r += 4) s += __half2float(h2[r * 64 + f]);
    sh[seg][f] = s;
    __syncthreads();
    if (t < 64) {
        float p = sh[0][t] + sh[1][t] + sh[2][t] + sh[3][t];
        pl[t] = p / fmaxf((float)(end - beg), 1.0f);
    }
    __syncthreads();
    if (t < 4) {
        float l = bfc[t];
#pragma unroll
        for (int k = 0; k < 64; ++k) l += pl[k] * Wfc[k * 4 + t];
        lg[t] = l;
    }
    __syncthreads();
    if (t == 0) {
        float l0 = lg[0], l1 = lg[1], l2 = lg[2], l3 = lg[3];
        float m = fmaxf(fmaxf(l0, l1), fmaxf(l2, l3));
        float ss = expf(l0 - m) + expf(l1 - m) + expf(l2 - m) + expf(l3 - m);
        float lse = m + logf(ss);
        out[g * 4 + 0] = l0 - lse;
        out[g * 4 + 1] = l1 - lse;
        out[g * 4 + 2] = l2 - lse;
        out[g * 4 + 3] = l3 - lse;
        out[N_GRAPHS * 4 + g] = (float)y[g];
    }
}

extern "C" void kernel_launch(void* const* d_in, const int* in_sizes, int n_in,
                              void* d_out, int out_size, void* d_ws, size_t ws_size,
                              hipStream_t stream) {
    const float* x     = (const float*)d_in[0];
    const int*   ei    = (const int*)d_in[1];
    const int*   batch = (const int*)d_in[2];
    const int*   y     = (const int*)d_in[3];
    const float* W1    = (const float*)d_in[4];
    const float* b1    = (const float*)d_in[5];
    const float* W2    = (const float*)d_in[6];
    const float* b2    = (const float*)d_in[7];
    const float* Wfc   = (const float*)d_in[8];
    const float* bfc   = (const float*)d_in[9];
    float* out = (float*)d_out;

    const int* src = ei;
    const int* dst = ei + N_EDGES;

    char* wsb = (char*)d_ws;
    int*          bcnt   = (int*)(wsb + OFF_BCNT);
    float*        dinv   = (float*)(wsb + OFF_DINV);
    int2*         offs2  = (int2*)(wsb + OFF_OFFS2);
    unsigned int* tmp    = (unsigned int*)(wsb + OFF_TMP);
    int*          sorted = (int*)(wsb + OFF_SORTED);
    unsigned int* xs8_1  = (unsigned int*)(wsb + OFF_XS8_1);
    unsigned int* xs8_2  = (unsigned int*)(wsb + OFF_XS8_2);
    __half*       h2     = (__half*)(wsb + OFF_H2);

    hipMemsetAsync(bcnt, 0, 1024u, stream);

    binA<<<NBKT, 256, 0, stream>>>(src, dst, bcnt, tmp, xs8_1, xs8_2);
    binB2<<<NBKT, 256, 0, stream>>>(tmp, bcnt, sorted, offs2, dinv);

    // layer 1: 128 -> 64
    gemm1<<<N_NODES / 16, 256, 0, stream>>>(x, W1, dinv, xs8_1);
    // layer-1 aggregate + relu + fused W2 GEMM -> xs8_2
    gather_fuse<<<N_NODES / 16, 256, 0, stream>>>((const unsigned char*)xs8_1, offs2, sorted,
                                                  dinv, b1, W2, xs8_2);
    // layer-2 aggregate + relu -> h2 (fp16)
    gather_h2<<<N_NODES / 16, 256, 0, stream>>>((const unsigned char*)xs8_2, offs2, sorted,
                                                dinv, b2, h2);

    pool_head<<<N_GRAPHS, 256, 0, stream>>>(h2, batch, Wfc, bfc, y, out);
}